// Round 10
// baseline (229.854 us; speedup 1.0000x reference)
//
#include <hip/hip_runtime.h>
#include <math.h>

// Problem dims (fixed)
#define NB 16
#define NV 12
#define NROWS 192          // NB*NV
#define DRAW 200704
#define KOUT 256
#define DFEAT 1024
#define NG 8
#define NCLS 40

// K1: 512 blocks = 256 K-chunks x 2 col-halves. KC=784 -> 25 steps of BK=32.
#define NCHUNK 256
#define KC 784

// LDS (bytes), single buffer: A 12 tiles x 2048 (1KB hi + 1KB lo), B 8 x 2048
#define ABASE 0
#define BBASE 24576

// workspace layout (bytes)
#define WS_SCORE 0                       // [192] f32
#define WS_DESC  1024                    // [16][1024] f32
#define WS_Z1    66560                   // [16][512] f32
#define WS_Z2    99328                   // [16][256] f32
#define WS_PART  131072                  // [192 rows][256 chunks][256 cols] f32

typedef __attribute__((ext_vector_type(8))) short short8;
typedef __attribute__((ext_vector_type(4))) float f32x4;

// split x -> hi(bf16 trunc) + lo(bf16 trunc of exact residual); pack 4 elems
__device__ __forceinline__ void cvt4(float4 v, uint2& hi, uint2& lo) {
    unsigned b0 = __float_as_uint(v.x), b1 = __float_as_uint(v.y);
    unsigned b2 = __float_as_uint(v.z), b3 = __float_as_uint(v.w);
    hi.x = (b0 >> 16) | (b1 & 0xffff0000u);
    hi.y = (b2 >> 16) | (b3 & 0xffff0000u);
    float r0 = v.x - __uint_as_float(b0 & 0xffff0000u);
    float r1 = v.y - __uint_as_float(b1 & 0xffff0000u);
    float r2 = v.z - __uint_as_float(b2 & 0xffff0000u);
    float r3 = v.w - __uint_as_float(b3 & 0xffff0000u);
    lo.x = (__float_as_uint(r0) >> 16) | (__float_as_uint(r1) & 0xffff0000u);
    lo.y = (__float_as_uint(r2) >> 16) | (__float_as_uint(r3) & 0xffff0000u);
}

// issue step-S1 global loads into named reg buffers (R4-exact)
#define K1_LOAD(DA, DB, S1)                                                    \
  {                                                                            \
    const int koff = (S1) * 32;                                                \
    _Pragma("unroll") for (int p = 0; p < 3; ++p) {                            \
      bool ok = aact[p] && (akq[p] * 4 + koff < KC);                           \
      DA[p] = ok ? *(const float4*)(aptr[p] + koff)                            \
                 : make_float4(0.f, 0.f, 0.f, 0.f);                            \
    }                                                                          \
    _Pragma("unroll") for (int q = 0; q < 8; ++q) {                            \
      int dd = bkh * 8 + q + koff;                                             \
      DB[q] = (dd < KC) ? bptr[(size_t)(koff + q) * KOUT] : 0.f;               \
    }                                                                          \
  }

// one K-step (R4-exact discipline): raw top barrier (no vmcnt drain), issue
// next loads (stay in flight through MFMA), cvt+stage cur, lgkm+barrier,
// fragment reads + 36 MFMAs.
#define K1_STEP(CA, CB, NA, NB_, S, DOLOAD)                                    \
  {                                                                            \
    __builtin_amdgcn_sched_barrier(0);                                         \
    __builtin_amdgcn_s_barrier();                                              \
    __builtin_amdgcn_sched_barrier(0);                                         \
    if (DOLOAD) K1_LOAD(NA, NB_, (S) + 1);                                     \
    _Pragma("unroll") for (int p = 0; p < 3; ++p) {                            \
      uint2 hi, lo; cvt4(CA[p], hi, lo);                                       \
      *(uint2*)(smem + awoff[p]) = hi;                                         \
      *(uint2*)(smem + awoff[p] + 1024) = lo;                                  \
    }                                                                          \
    {                                                                          \
      uint2 h0, l0, h1, l1;                                                    \
      cvt4(make_float4(CB[0], CB[1], CB[2], CB[3]), h0, l0);                   \
      cvt4(make_float4(CB[4], CB[5], CB[6], CB[7]), h1, l1);                   \
      uint4 hv; hv.x = h0.x; hv.y = h0.y; hv.z = h1.x; hv.w = h1.y;            \
      uint4 lv; lv.x = l0.x; lv.y = l0.y; lv.z = l1.x; lv.w = l1.y;            \
      *(uint4*)(smem + bwoff) = hv;                                            \
      *(uint4*)(smem + bwoff + 1024) = lv;                                     \
    }                                                                          \
    asm volatile("s_waitcnt lgkmcnt(0)" ::: "memory");                         \
    __builtin_amdgcn_s_barrier();                                              \
    __builtin_amdgcn_sched_barrier(0);                                         \
    short8 ah[3], al[3];                                                       \
    _Pragma("unroll") for (int tm = 0; tm < 3; ++tm) {                         \
      int off = ABASE + (wm * 3 + tm) * 2048 + aroff;                          \
      ah[tm] = *(const short8*)(smem + off);                                   \
      al[tm] = *(const short8*)(smem + off + 1024);                            \
    }                                                                          \
    _Pragma("unroll") for (int tn = 0; tn < 4; ++tn) {                         \
      int off = BBASE + (wn * 4 + tn) * 2048 + ((lane << 4) ^ ((tn & 1) << 6));\
      short8 bh = *(const short8*)(smem + off);                                \
      short8 bl = *(const short8*)(smem + off + 1024);                         \
      _Pragma("unroll") for (int tm = 0; tm < 3; ++tm) {                       \
        acc[tm][tn] = __builtin_amdgcn_mfma_f32_16x16x32_bf16(ah[tm], bh, acc[tm][tn], 0, 0, 0); \
        acc[tm][tn] = __builtin_amdgcn_mfma_f32_16x16x32_bf16(ah[tm], bl, acc[tm][tn], 0, 0, 0); \
        acc[tm][tn] = __builtin_amdgcn_mfma_f32_16x16x32_bf16(al[tm], bh, acc[tm][tn], 0, 0, 0); \
      }                                                                        \
    }                                                                          \
  }

// MFMA split-K/split-N GEMM (R4-exact, measured 131us). Co-XCD bid map: both
// col-halves of a chunk share bid%8 (same XCD L2 for A reuse). 8 waves
// 4(M)x2(N); wave owns 48 rows x 64 cols = 3x4 fragments. bf16x3.
__global__ __launch_bounds__(512, 4)
void k1_mfma(const float* __restrict__ raw, const float* __restrict__ W1,
             const int* __restrict__ vnum, float* __restrict__ part)
{
    __shared__ __align__(16) char smem[40960];
    __shared__ char act[NROWS];
    const int t = threadIdx.x;
    const int g8 = blockIdx.x & 7;
    const int i8 = blockIdx.x >> 3;
    const int c = g8 * 32 + (i8 >> 1);
    const int colbase = (i8 & 1) * 128;
    const int d0 = c * KC;
    if (t < NROWS) act[t] = ((t % NV) < vnum[t / NV]) ? 1 : 0;
    __syncthreads();

    // ---- A staging geometry: 3 passes, idx=p*512+t: row=idx>>3, kq=idx&7 ----
    int akq[3];
    bool aact[3];
    const float* aptr[3];
    int awoff[3];
#pragma unroll
    for (int p = 0; p < 3; ++p) {
        int idx = p * 512 + t;
        int row = idx >> 3, kq = idx & 7;
        akq[p] = kq;
        aact[p] = act[row] != 0;
        aptr[p] = raw + (size_t)row * DRAW + d0 + kq * 4;
        int off = ABASE + (row >> 4) * 2048 + (((row & 15) + ((kq >> 1) << 4)) << 4) + ((kq & 1) << 3);
        off ^= ((kq >> 1) & 1) << 6;
        awoff[p] = off;
    }
    // ---- B staging: col = t&127 (within half), bkh = t>>7 (8 k each) ----
    const int bcol = t & 127;
    const int bkh = t >> 7;
    const float* bptr = W1 + (size_t)(d0 + bkh * 8) * KOUT + colbase + bcol;
    const int bTN = bcol >> 4;
    int bwoff = BBASE + bTN * 2048 + (((bcol & 15) + (bkh << 4)) << 4);
    bwoff ^= (bTN & 1) << 6;

    // wave/fragment geometry
    const int lane = t & 63;
    const int wave = t >> 6;
    const int wm = wave >> 1, wn = wave & 1;
    const int aroff = (lane << 4) ^ (((lane >> 4) & 1) << 6);

    f32x4 acc[3][4];
#pragma unroll
    for (int i = 0; i < 3; ++i)
#pragma unroll
        for (int j = 0; j < 4; ++j) acc[i][j] = (f32x4){0.f, 0.f, 0.f, 0.f};

    float4 A0[3], A1[3];
    float B0r[8], B1r[8];
    K1_LOAD(A0, B0r, 0);

#pragma unroll 1
    for (int sp = 0; sp < 12; ++sp) {
        K1_STEP(A0, B0r, A1, B1r, 2 * sp, 1);
        K1_STEP(A1, B1r, A0, B0r, 2 * sp + 1, 1);
    }
    K1_STEP(A0, B0r, A1, B1r, 24, 0);

    // ---- epilogue: part[row][chunk][col] (contiguous per-row reduce stream);
    // C/D layout col=lane&15, row=(lane>>4)*4+r
#pragma unroll
    for (int tm = 0; tm < 3; ++tm) {
        int row0 = wm * 48 + tm * 16 + ((lane >> 4) << 2);
#pragma unroll
        for (int tn = 0; tn < 4; ++tn) {
            int col = colbase + wn * 64 + tn * 16 + (lane & 15);
            f32x4 a = acc[tm][tn];
#pragma unroll
            for (int r = 0; r < 4; ++r)
                part[((size_t)(row0 + r) * NCHUNK + c) * KOUT + col] = a[r];
        }
    }
}

// fused 256-chunk reduce + score head. One block per row; part[row] is a
// CONTIGUOUS 256KB stream -> coalesced. (verified R7)
__global__ __launch_bounds__(1024)
void k2_score(const float* __restrict__ part, const float* __restrict__ b1,
              const float* __restrict__ W2, const float* __restrict__ b2,
              float* __restrict__ score)
{
    const int row = blockIdx.x, t = threadIdx.x;
    const int col = t & 255, cg = t >> 8;
    __shared__ float red[4][KOUT];
    __shared__ float r2[4];
    const float* p = part + ((size_t)row * NCHUNK + cg * 64) * KOUT + col;
    float s = 0.f;
#pragma unroll 8
    for (int i = 0; i < 64; ++i) s += p[(size_t)i * KOUT];
    red[cg][col] = s;
    __syncthreads();
    if (t < 256) {
        float v = red[0][col] + red[1][col] + red[2][col] + red[3][col];
        float h = fmaxf(v + b1[col], 0.f) * W2[col];
        for (int o = 32; o > 0; o >>= 1) h += __shfl_down(h, o, 64);
        if ((t & 63) == 0) r2[t >> 6] = h;
    }
    __syncthreads();
    if (t == 0) {
        float sm = r2[0] + r2[1] + r2[2] + r2[3];
        float sraw = fmaxf(sm + b2[0], 0.f);
        score[row] = 1.f / (1.f + expf(-tanhf(fabsf(sraw))));
    }
}

// binning -> per-view coeff -> desc. One block per sample. (verified R6)
__global__ __launch_bounds__(512)
void k3_bindesc(const float* __restrict__ score, const int* __restrict__ vnum,
                const float* __restrict__ fv, float* __restrict__ desc)
{
    const int n = blockIdx.x, t = threadIdx.x;
    __shared__ float coeffL[NV], wsum[NG], wt[NG], wtotS;
    __shared__ int cnt[NG];
    if (t < NG) { cnt[t] = 0; wsum[t] = 0.f; }
    __syncthreads();
    const int vn = vnum[n];
    const bool act = (t < NV) && (t < vn);
    float sc = 0.f; int b = 0;
    if (act) {
        sc = score[n * NV + t];
        b = (int)floorf(sc * 8.f); b = b < 0 ? 0 : (b > 7 ? 7 : b);
        atomicAdd(&cnt[b], 1);
    }
    __syncthreads();
    if (act) atomicAdd(&wsum[b], ceilf(sc * (float)cnt[b]));  // integer-valued: order-exact
    __syncthreads();
    if (t < NG) wt[t] = (cnt[t] > 0) ? wsum[t] / (float)cnt[t] : 0.f;
    __syncthreads();
    if (t == 0) { float x = 0.f; for (int g = 0; g < NG; ++g) x += wt[g]; wtotS = x; }
    __syncthreads();
    if (t < NV) coeffL[t] = act ? wt[b] / ((float)cnt[b] * wtotS) : 0.f;
    __syncthreads();
#pragma unroll
    for (int p = 0; p < 2; ++p) {
        int d = t + p * 512;
        float a = 0.f;
#pragma unroll
        for (int v = 0; v < NV; ++v)
            a = fmaf(coeffL[v], fv[((size_t)n * NV + v) * DFEAT + d], a);
        desc[n * DFEAT + d] = a;
    }
}

// z1 = relu(desc @ Wf1 + bf1): j-sliced blocks, all 16 samples inside the
// block -> Wf1 read once overall. block 512 = 64 j x 8 sample-pairs. (verified R5/R6)
__global__ __launch_bounds__(512)
void kz1(const float* __restrict__ desc, const float* __restrict__ Wf1,
         const float* __restrict__ bf1, float* __restrict__ z1)
{
    __shared__ float dL[NB * DFEAT];
    const int t = threadIdx.x;
#pragma unroll
    for (int i = 0; i < 8; ++i)
        *(float4*)&dL[(i * 512 + t) * 4] = *(const float4*)&desc[(i * 512 + t) * 4];
    __syncthreads();
    const int j = blockIdx.x * 64 + (t & 63);
    const int n0 = (t >> 6) * 2;
    float a0 = 0.f, a1 = 0.f, a2 = 0.f, a3 = 0.f;
#pragma unroll 4
    for (int d = 0; d < DFEAT; d += 2) {
        float w0 = Wf1[(size_t)d * 512 + j];
        float w1 = Wf1[(size_t)(d + 1) * 512 + j];
        a0 = fmaf(dL[n0 * DFEAT + d], w0, a0);
        a1 = fmaf(dL[(n0 + 1) * DFEAT + d], w0, a1);
        a2 = fmaf(dL[n0 * DFEAT + d + 1], w1, a2);
        a3 = fmaf(dL[(n0 + 1) * DFEAT + d + 1], w1, a3);
    }
    z1[n0 * 512 + j] = fmaxf(a0 + a2 + bf1[j], 0.f);
    z1[(n0 + 1) * 512 + j] = fmaxf(a1 + a3 + bf1[j], 0.f);
}

// z2 = relu(z1 @ Wf2 + bf2)  (verified R5/R6)
__global__ __launch_bounds__(512)
void kz2(const float* __restrict__ z1, const float* __restrict__ Wf2,
         const float* __restrict__ bf2, float* __restrict__ z2)
{
    __shared__ float zL[NB * 512];
    const int t = threadIdx.x;
#pragma unroll
    for (int i = 0; i < 4; ++i)
        *(float4*)&zL[(i * 512 + t) * 4] = *(const float4*)&z1[(i * 512 + t) * 4];
    __syncthreads();
    const int j = blockIdx.x * 64 + (t & 63);
    const int n0 = (t >> 6) * 2;
    float a0 = 0.f, a1 = 0.f, a2 = 0.f, a3 = 0.f;
#pragma unroll 4
    for (int d = 0; d < 512; d += 2) {
        float w0 = Wf2[(size_t)d * 256 + j];
        float w1 = Wf2[(size_t)(d + 1) * 256 + j];
        a0 = fmaf(zL[n0 * 512 + d], w0, a0);
        a1 = fmaf(zL[(n0 + 1) * 512 + d], w0, a1);
        a2 = fmaf(zL[n0 * 512 + d + 1], w1, a2);
        a3 = fmaf(zL[(n0 + 1) * 512 + d + 1], w1, a3);
    }
    z2[n0 * 256 + j] = fmaxf(a0 + a2 + bf2[j], 0.f);
    z2[(n0 + 1) * 256 + j] = fmaxf(a1 + a3 + bf2[j], 0.f);
}

// out = z2 @ Wl + bl  (verified R5/R6)
__global__ __launch_bounds__(640)
void kout(const float* __restrict__ z2, const float* __restrict__ Wl,
          const float* __restrict__ bl, float* __restrict__ out)
{
    const int t = threadIdx.x;
    const int n = t / NCLS, j = t % NCLS;
    float a = 0.f;
    for (int d = 0; d < 256; ++d)
        a = fmaf(z2[n * 256 + d], Wl[d * NCLS + j], a);
    out[t] = a + bl[j];
}

extern "C" void kernel_launch(void* const* d_in, const int* in_sizes, int n_in,
                              void* d_out, int out_size, void* d_ws, size_t ws_size,
                              hipStream_t stream)
{
    const float* raw  = (const float*)d_in[0];
    const float* fv   = (const float*)d_in[1];
    const int*   vnum = (const int*)d_in[2];
    const float* W1   = (const float*)d_in[3];
    const float* b1   = (const float*)d_in[4];
    const float* W2   = (const float*)d_in[5];
    const float* b2   = (const float*)d_in[6];
    const float* Wf1  = (const float*)d_in[7];
    const float* bf1  = (const float*)d_in[8];
    const float* Wf2  = (const float*)d_in[9];
    const float* bf2  = (const float*)d_in[10];
    const float* Wl   = (const float*)d_in[11];
    const float* bl   = (const float*)d_in[12];
    float* out = (float*)d_out;
    char* ws = (char*)d_ws;
    float* score = (float*)(ws + WS_SCORE);
    float* desc  = (float*)(ws + WS_DESC);
    float* z1    = (float*)(ws + WS_Z1);
    float* z2    = (float*)(ws + WS_Z2);
    float* part  = (float*)(ws + WS_PART);

    k1_mfma<<<2 * NCHUNK, 512, 0, stream>>>(raw, W1, vnum, part);
    k2_score<<<NROWS, 1024, 0, stream>>>(part, b1, W2, b2, score);
    k3_bindesc<<<NB, 512, 0, stream>>>(score, vnum, fv, desc);
    kz1<<<8, 512, 0, stream>>>(desc, Wf1, bf1, z1);
    kz2<<<4, 512, 0, stream>>>(z1, Wf2, bf2, z2);
    kout<<<1, 640, 0, stream>>>(z2, Wl, bl, out);
}

// Round 11
// 188.107 us; speedup vs baseline: 1.2219x; 1.2219x over previous
//
#include <hip/hip_runtime.h>
#include <math.h>

// Problem dims (fixed)
#define NB 16
#define NV 12
#define NROWS 192          // NB*NV
#define DRAW 200704
#define KOUT 256
#define DFEAT 1024
#define NG 8
#define NCLS 40

// K1: 512 blocks = 256 K-chunks x 2 col-halves. KC=784 -> 25 steps of BK=32.
#define NCHUNK 256
#define KC 784

// LDS (bytes), single buffer: A 12 tiles x 2048 (1KB hi + 1KB lo), B 8 x 2048
#define ABASE 0
#define BBASE 24576

// workspace layout (bytes)
#define WS_SCORE 0                       // [192] f32
#define WS_PART  4096                    // [192 rows][256 chunks][256 cols] f32

typedef __attribute__((ext_vector_type(8))) short short8;
typedef __attribute__((ext_vector_type(4))) float f32x4;

// split x -> hi(bf16 trunc) + lo(bf16 trunc of exact residual); pack 4 elems
__device__ __forceinline__ void cvt4(float4 v, uint2& hi, uint2& lo) {
    unsigned b0 = __float_as_uint(v.x), b1 = __float_as_uint(v.y);
    unsigned b2 = __float_as_uint(v.z), b3 = __float_as_uint(v.w);
    hi.x = (b0 >> 16) | (b1 & 0xffff0000u);
    hi.y = (b2 >> 16) | (b3 & 0xffff0000u);
    float r0 = v.x - __uint_as_float(b0 & 0xffff0000u);
    float r1 = v.y - __uint_as_float(b1 & 0xffff0000u);
    float r2 = v.z - __uint_as_float(b2 & 0xffff0000u);
    float r3 = v.w - __uint_as_float(b3 & 0xffff0000u);
    lo.x = (__float_as_uint(r0) >> 16) | (__float_as_uint(r1) & 0xffff0000u);
    lo.y = (__float_as_uint(r2) >> 16) | (__float_as_uint(r3) & 0xffff0000u);
}

// issue step-S1 global loads into named reg buffers (R4-exact)
#define K1_LOAD(DA, DB, S1)                                                    \
  {                                                                            \
    const int koff = (S1) * 32;                                                \
    _Pragma("unroll") for (int p = 0; p < 3; ++p) {                            \
      bool ok = aact[p] && (akq[p] * 4 + koff < KC);                           \
      DA[p] = ok ? *(const float4*)(aptr[p] + koff)                            \
                 : make_float4(0.f, 0.f, 0.f, 0.f);                            \
    }                                                                          \
    _Pragma("unroll") for (int q = 0; q < 8; ++q) {                            \
      int dd = bkh * 8 + q + koff;                                             \
      DB[q] = (dd < KC) ? bptr[(size_t)(koff + q) * KOUT] : 0.f;               \
    }                                                                          \
  }

// one K-step (R4-exact discipline): raw top barrier (no vmcnt drain), issue
// next loads (stay in flight through MFMA), cvt+stage cur, lgkm+barrier,
// fragment reads + 36 MFMAs.
#define K1_STEP(CA, CB, NA, NB_, S, DOLOAD)                                    \
  {                                                                            \
    __builtin_amdgcn_sched_barrier(0);                                         \
    __builtin_amdgcn_s_barrier();                                              \
    __builtin_amdgcn_sched_barrier(0);                                         \
    if (DOLOAD) K1_LOAD(NA, NB_, (S) + 1);                                     \
    _Pragma("unroll") for (int p = 0; p < 3; ++p) {                            \
      uint2 hi, lo; cvt4(CA[p], hi, lo);                                       \
      *(uint2*)(smem + awoff[p]) = hi;                                         \
      *(uint2*)(smem + awoff[p] + 1024) = lo;                                  \
    }                                                                          \
    {                                                                          \
      uint2 h0, l0, h1, l1;                                                    \
      cvt4(make_float4(CB[0], CB[1], CB[2], CB[3]), h0, l0);                   \
      cvt4(make_float4(CB[4], CB[5], CB[6], CB[7]), h1, l1);                   \
      uint4 hv; hv.x = h0.x; hv.y = h0.y; hv.z = h1.x; hv.w = h1.y;            \
      uint4 lv; lv.x = l0.x; lv.y = l0.y; lv.z = l1.x; lv.w = l1.y;            \
      *(uint4*)(smem + bwoff) = hv;                                            \
      *(uint4*)(smem + bwoff + 1024) = lv;                                     \
    }                                                                          \
    asm volatile("s_waitcnt lgkmcnt(0)" ::: "memory");                         \
    __builtin_amdgcn_s_barrier();                                              \
    __builtin_amdgcn_sched_barrier(0);                                         \
    short8 ah[3], al[3];                                                       \
    _Pragma("unroll") for (int tm = 0; tm < 3; ++tm) {                         \
      int off = ABASE + (wm * 3 + tm) * 2048 + aroff;                          \
      ah[tm] = *(const short8*)(smem + off);                                   \
      al[tm] = *(const short8*)(smem + off + 1024);                            \
    }                                                                          \
    _Pragma("unroll") for (int tn = 0; tn < 4; ++tn) {                         \
      int off = BBASE + (wn * 4 + tn) * 2048 + ((lane << 4) ^ ((tn & 1) << 6));\
      short8 bh = *(const short8*)(smem + off);                                \
      short8 bl = *(const short8*)(smem + off + 1024);                         \
      _Pragma("unroll") for (int tm = 0; tm < 3; ++tm) {                       \
        acc[tm][tn] = __builtin_amdgcn_mfma_f32_16x16x32_bf16(ah[tm], bh, acc[tm][tn], 0, 0, 0); \
        acc[tm][tn] = __builtin_amdgcn_mfma_f32_16x16x32_bf16(ah[tm], bl, acc[tm][tn], 0, 0, 0); \
        acc[tm][tn] = __builtin_amdgcn_mfma_f32_16x16x32_bf16(al[tm], bh, acc[tm][tn], 0, 0, 0); \
      }                                                                        \
    }                                                                          \
  }

// MFMA split-K/split-N GEMM (R4-exact schedule, measured 134us). Co-XCD bid
// map: both col-halves of a chunk share bid%8 (same XCD L2 for A reuse).
// 8 waves 4(M)x2(N); wave owns 48 rows x 64 cols = 3x4 fragments. bf16x3.
__global__ __launch_bounds__(512, 4)
void k1_mfma(const float* __restrict__ raw, const float* __restrict__ W1,
             const int* __restrict__ vnum, float* __restrict__ part)
{
    __shared__ __align__(16) char smem[40960];
    __shared__ char act[NROWS];
    const int t = threadIdx.x;
    const int g8 = blockIdx.x & 7;
    const int i8 = blockIdx.x >> 3;
    const int c = g8 * 32 + (i8 >> 1);
    const int colbase = (i8 & 1) * 128;
    const int d0 = c * KC;
    if (t < NROWS) act[t] = ((t % NV) < vnum[t / NV]) ? 1 : 0;
    __syncthreads();

    // ---- A staging geometry: 3 passes, idx=p*512+t: row=idx>>3, kq=idx&7 ----
    int akq[3];
    bool aact[3];
    const float* aptr[3];
    int awoff[3];
#pragma unroll
    for (int p = 0; p < 3; ++p) {
        int idx = p * 512 + t;
        int row = idx >> 3, kq = idx & 7;
        akq[p] = kq;
        aact[p] = act[row] != 0;
        aptr[p] = raw + (size_t)row * DRAW + d0 + kq * 4;
        int off = ABASE + (row >> 4) * 2048 + (((row & 15) + ((kq >> 1) << 4)) << 4) + ((kq & 1) << 3);
        off ^= ((kq >> 1) & 1) << 6;
        awoff[p] = off;
    }
    // ---- B staging: col = t&127 (within half), bkh = t>>7 (8 k each) ----
    const int bcol = t & 127;
    const int bkh = t >> 7;
    const float* bptr = W1 + (size_t)(d0 + bkh * 8) * KOUT + colbase + bcol;
    const int bTN = bcol >> 4;
    int bwoff = BBASE + bTN * 2048 + (((bcol & 15) + (bkh << 4)) << 4);
    bwoff ^= (bTN & 1) << 6;

    // wave/fragment geometry
    const int lane = t & 63;
    const int wave = t >> 6;
    const int wm = wave >> 1, wn = wave & 1;
    const int aroff = (lane << 4) ^ (((lane >> 4) & 1) << 6);

    f32x4 acc[3][4];
#pragma unroll
    for (int i = 0; i < 3; ++i)
#pragma unroll
        for (int j = 0; j < 4; ++j) acc[i][j] = (f32x4){0.f, 0.f, 0.f, 0.f};

    float4 A0[3], A1[3];
    float B0r[8], B1r[8];
    K1_LOAD(A0, B0r, 0);

#pragma unroll 1
    for (int sp = 0; sp < 12; ++sp) {
        K1_STEP(A0, B0r, A1, B1r, 2 * sp, 1);
        K1_STEP(A1, B1r, A0, B0r, 2 * sp + 1, 1);
    }
    K1_STEP(A0, B0r, A1, B1r, 24, 0);

    // ---- epilogue: part[row][chunk][col] (contiguous per-row reduce stream);
    // C/D layout col=lane&15, row=(lane>>4)*4+r
#pragma unroll
    for (int tm = 0; tm < 3; ++tm) {
        int row0 = wm * 48 + tm * 16 + ((lane >> 4) << 2);
#pragma unroll
        for (int tn = 0; tn < 4; ++tn) {
            int col = colbase + wn * 64 + tn * 16 + (lane & 15);
            f32x4 a = acc[tm][tn];
#pragma unroll
            for (int r = 0; r < 4; ++r)
                part[((size_t)(row0 + r) * NCHUNK + c) * KOUT + col] = a[r];
        }
    }
}

// fused 256-chunk reduce + score head. One block per row; part[row] is a
// CONTIGUOUS 256KB stream -> coalesced. (verified R7/R10)
__global__ __launch_bounds__(1024)
void k2_score(const float* __restrict__ part, const float* __restrict__ b1,
              const float* __restrict__ W2, const float* __restrict__ b2,
              float* __restrict__ score)
{
    const int row = blockIdx.x, t = threadIdx.x;
    const int col = t & 255, cg = t >> 8;
    __shared__ float red[4][KOUT];
    __shared__ float r2[4];
    const float* p = part + ((size_t)row * NCHUNK + cg * 64) * KOUT + col;
    float s = 0.f;
#pragma unroll 8
    for (int i = 0; i < 64; ++i) s += p[(size_t)i * KOUT];
    red[cg][col] = s;
    __syncthreads();
    if (t < 256) {
        float v = red[0][col] + red[1][col] + red[2][col] + red[3][col];
        float h = fmaxf(v + b1[col], 0.f) * W2[col];
        for (int o = 32; o > 0; o >>= 1) h += __shfl_down(h, o, 64);
        if ((t & 63) == 0) r2[t >> 6] = h;
    }
    __syncthreads();
    if (t == 0) {
        float sm = r2[0] + r2[1] + r2[2] + r2[3];
        float sraw = fmaxf(sm + b2[0], 0.f);
        score[row] = 1.f / (1.f + expf(-tanhf(fabsf(sraw))));
    }
}

// fused tail: binning->coeff->desc->3-layer classifier. One block per sample.
// (verified R4/R9; redundant weight reads hit L2/L3 -- cheaper than extra
// kernel launches, measured R9 vs R10)
__global__ __launch_bounds__(512)
void k5f(const float* __restrict__ score, const int* __restrict__ vnum,
         const float* __restrict__ fv,
         const float* __restrict__ Wf1, const float* __restrict__ bf1,
         const float* __restrict__ Wf2, const float* __restrict__ bf2,
         const float* __restrict__ Wl,  const float* __restrict__ bl,
         float* __restrict__ out)
{
    const int n = blockIdx.x, t = threadIdx.x;
    __shared__ float coeffL[NV], descL[DFEAT], z1L[512], z2L[256];
    __shared__ float wsum[NG], wt[NG], outred[8][NCLS];
    __shared__ int cnt[NG];
    __shared__ float wtotS;
    if (t < NG) { cnt[t] = 0; wsum[t] = 0.f; }
    __syncthreads();
    const int vn = vnum[n];
    const bool act = (t < NV) && (t < vn);
    float sc = 0.f; int b = 0;
    if (act) {
        sc = score[n * NV + t];
        b = (int)floorf(sc * 8.f); b = b < 0 ? 0 : (b > 7 ? 7 : b);
        atomicAdd(&cnt[b], 1);
    }
    __syncthreads();
    if (act) atomicAdd(&wsum[b], ceilf(sc * (float)cnt[b]));
    __syncthreads();
    if (t < NG) wt[t] = (cnt[t] > 0) ? wsum[t] / (float)cnt[t] : 0.f;
    __syncthreads();
    if (t == 0) { float x = 0.f; for (int g = 0; g < NG; ++g) x += wt[g]; wtotS = x; }
    __syncthreads();
    if (t < NV) coeffL[t] = act ? wt[b] / ((float)cnt[b] * wtotS) : 0.f;
    __syncthreads();
#pragma unroll
    for (int p = 0; p < 2; ++p) {
        int d = t + p * 512;
        float a = 0.f;
#pragma unroll
        for (int v = 0; v < NV; ++v)
            a = fmaf(coeffL[v], fv[((size_t)n * NV + v) * DFEAT + d], a);
        descL[d] = a;
    }
    __syncthreads();
    {
        float a = 0.f;
#pragma unroll 8
        for (int d = 0; d < DFEAT; ++d)
            a = fmaf(descL[d], Wf1[(size_t)d * 512 + t], a);
        z1L[t] = fmaxf(a + bf1[t], 0.f);
    }
    __syncthreads();
    if (t < 256) {
        float a = 0.f;
#pragma unroll 8
        for (int d = 0; d < 512; ++d)
            a = fmaf(z1L[d], Wf2[(size_t)d * 256 + t], a);
        z2L[t] = fmaxf(a + bf2[t], 0.f);
    }
    __syncthreads();
    if (t < 320) {
        int j = t % NCLS, seg = t / NCLS;
        float a = 0.f;
#pragma unroll
        for (int dd = 0; dd < 32; ++dd) {
            int d = seg * 32 + dd;
            a = fmaf(z2L[d], Wl[d * NCLS + j], a);
        }
        outred[seg][j] = a;
    }
    __syncthreads();
    if (t < NCLS) {
        float a = bl[t];
#pragma unroll
        for (int s8 = 0; s8 < 8; ++s8) a += outred[s8][t];
        out[n * NCLS + t] = a;
    }
}

extern "C" void kernel_launch(void* const* d_in, const int* in_sizes, int n_in,
                              void* d_out, int out_size, void* d_ws, size_t ws_size,
                              hipStream_t stream)
{
    const float* raw  = (const float*)d_in[0];
    const float* fv   = (const float*)d_in[1];
    const int*   vnum = (const int*)d_in[2];
    const float* W1   = (const float*)d_in[3];
    const float* b1   = (const float*)d_in[4];
    const float* W2   = (const float*)d_in[5];
    const float* b2   = (const float*)d_in[6];
    const float* Wf1  = (const float*)d_in[7];
    const float* bf1  = (const float*)d_in[8];
    const float* Wf2  = (const float*)d_in[9];
    const float* bf2  = (const float*)d_in[10];
    const float* Wl   = (const float*)d_in[11];
    const float* bl   = (const float*)d_in[12];
    float* out = (float*)d_out;
    char* ws = (char*)d_ws;
    float* score = (float*)(ws + WS_SCORE);
    float* part  = (float*)(ws + WS_PART);

    k1_mfma<<<2 * NCHUNK, 512, 0, stream>>>(raw, W1, vnum, part);
    k2_score<<<NROWS, 1024, 0, stream>>>(part, b1, W2, b2, score);
    k5f<<<NB, 512, 0, stream>>>(score, vnum, fv, Wf1, bf1, Wf2, bf2, Wl, bl, out);
}

// Round 12
// 180.332 us; speedup vs baseline: 1.2746x; 1.0431x over previous
//
#include <hip/hip_runtime.h>
#include <math.h>

// Problem dims (fixed)
#define NB 16
#define NV 12
#define NROWS 192          // NB*NV
#define DRAW 200704
#define KOUT 256
#define DFEAT 1024
#define NG 8
#define NCLS 40

// K1: 256 blocks, one K-chunk each (KC=784 -> 25 steps of BK=32), full 192x256.
#define NCHUNK 256
#define KC 784

// LDS (bytes), single buffer 57344:
// A: 6 Mtiles(32 rows) x [2 ksubs x (1KB hi + 1KB lo)] = 24576
// B: 8 Ntiles(32 cols) x [2 ksubs x (1KB hi + 1KB lo)] = 32768
#define ABASE 0
#define BBASE 24576

// workspace layout (bytes)
#define WS_SCORE 0                       // [192] f32
#define WS_PART  4096                    // [192 rows][256 chunks][256 cols] f32

typedef __attribute__((ext_vector_type(8))) short short8;
typedef __attribute__((ext_vector_type(16))) float f32x16;

// split x -> hi(bf16 trunc) + lo(bf16 trunc of exact residual); pack 4 elems
__device__ __forceinline__ void cvt4(float4 v, uint2& hi, uint2& lo) {
    unsigned b0 = __float_as_uint(v.x), b1 = __float_as_uint(v.y);
    unsigned b2 = __float_as_uint(v.z), b3 = __float_as_uint(v.w);
    hi.x = (b0 >> 16) | (b1 & 0xffff0000u);
    hi.y = (b2 >> 16) | (b3 & 0xffff0000u);
    float r0 = v.x - __uint_as_float(b0 & 0xffff0000u);
    float r1 = v.y - __uint_as_float(b1 & 0xffff0000u);
    float r2 = v.z - __uint_as_float(b2 & 0xffff0000u);
    float r3 = v.w - __uint_as_float(b3 & 0xffff0000u);
    lo.x = (__float_as_uint(r0) >> 16) | (__float_as_uint(r1) & 0xffff0000u);
    lo.y = (__float_as_uint(r2) >> 16) | (__float_as_uint(r3) & 0xffff0000u);
}

// issue step-S1 global loads into named reg buffers (guards R4-style)
#define K1_LOAD(DA, DB, S1)                                                    \
  {                                                                            \
    const int koff = (S1) * 32;                                                \
    _Pragma("unroll") for (int p = 0; p < 3; ++p) {                            \
      bool ok = aact[p] && (akq[p] * 4 + koff < KC);                           \
      DA[p] = ok ? *(const float4*)(aptr[p] + koff)                            \
                 : make_float4(0.f, 0.f, 0.f, 0.f);                            \
    }                                                                          \
    _Pragma("unroll") for (int q = 0; q < 16; ++q) {                           \
      int dd = ks + q + koff;                                                  \
      DB[q] = (dd < KC) ? bptr[(size_t)(koff + q) * KOUT] : 0.f;               \
    }                                                                          \
  }

// cvt regs -> LDS (single buffer)
#define K1_WRITE(CA, CB)                                                       \
  {                                                                            \
    _Pragma("unroll") for (int p = 0; p < 3; ++p) {                            \
      uint2 hi, lo; cvt4(CA[p], hi, lo);                                       \
      *(uint2*)(smem + awoff[p]) = hi;                                         \
      *(uint2*)(smem + awoff[p] + 1024) = lo;                                  \
    }                                                                          \
    _Pragma("unroll") for (int og = 0; og < 2; ++og) {                         \
      uint2 h0, l0, h1, l1;                                                    \
      cvt4(make_float4(CB[og*8+0], CB[og*8+1], CB[og*8+2], CB[og*8+3]), h0, l0); \
      cvt4(make_float4(CB[og*8+4], CB[og*8+5], CB[og*8+6], CB[og*8+7]), h1, l1); \
      uint4 hv; hv.x = h0.x; hv.y = h0.y; hv.z = h1.x; hv.w = h1.y;            \
      uint4 lv; lv.x = l0.x; lv.y = l0.y; lv.z = l1.x; lv.w = l1.y;            \
      *(uint4*)(smem + bwoff[og]) = hv;                                        \
      *(uint4*)(smem + bwoff[og] + 1024) = lv;                                 \
    }                                                                          \
  }

// fragment reads (all at lane*16: conflict-free) + 36 MFMAs of 32x32x16
// (2 ksubs x 3x2 frag-pairs x bf16x3)
#define K1_MMA()                                                               \
  {                                                                            \
    _Pragma("unroll") for (int kf = 0; kf < 2; ++kf) {                         \
      short8 ah[3], al[3];                                                     \
      _Pragma("unroll") for (int tm = 0; tm < 3; ++tm) {                       \
        int off = ABASE + (wm * 3 + tm) * 4096 + kf * 2048 + (lane << 4);      \
        ah[tm] = *(const short8*)(smem + off);                                 \
        al[tm] = *(const short8*)(smem + off + 1024);                          \
      }                                                                        \
      _Pragma("unroll") for (int tn = 0; tn < 2; ++tn) {                       \
        int off = BBASE + (wn * 2 + tn) * 4096 + kf * 2048 + (lane << 4);      \
        short8 bh = *(const short8*)(smem + off);                              \
        short8 bl = *(const short8*)(smem + off + 1024);                       \
        _Pragma("unroll") for (int tm = 0; tm < 3; ++tm) {                     \
          acc[tm][tn] = __builtin_amdgcn_mfma_f32_32x32x16_bf16(ah[tm], bh, acc[tm][tn], 0, 0, 0); \
          acc[tm][tn] = __builtin_amdgcn_mfma_f32_32x32x16_bf16(ah[tm], bl, acc[tm][tn], 0, 0, 0); \
          acc[tm][tn] = __builtin_amdgcn_mfma_f32_32x32x16_bf16(al[tm], bh, acc[tm][tn], 0, 0, 0); \
        }                                                                      \
      }                                                                        \
    }                                                                          \
  }

// one K-step (R4-exact discipline): raw top barrier (no vmcnt drain), issue
// next loads (stay in flight through MFMA), cvt+stage cur, lgkm+barrier, MMA.
#define K1_STEP(CA, CB, NA, NB_, S, DOLOAD)                                    \
  {                                                                            \
    __builtin_amdgcn_sched_barrier(0);                                         \
    __builtin_amdgcn_s_barrier();                                              \
    __builtin_amdgcn_sched_barrier(0);                                         \
    if (DOLOAD) K1_LOAD(NA, NB_, (S) + 1);                                     \
    K1_WRITE(CA, CB);                                                          \
    asm volatile("s_waitcnt lgkmcnt(0)" ::: "memory");                         \
    __builtin_amdgcn_s_barrier();                                              \
    __builtin_amdgcn_sched_barrier(0);                                         \
    K1_MMA();                                                                  \
  }

// MFMA split-K GEMM, 32x32x16, full-width blocks: block = one K-chunk,
// entire 192x256 output. 8 waves 2(M)x4(N); wave owns 96x64 = 3x2 fragments
// of 32x32. A staged once (not twice); all LDS fragment reads at lane*16
// (conflict-free). bf16x3: acc += ah*bh + ah*bl + al*bh.
__global__ __launch_bounds__(512, 2)
void k1_mfma(const float* __restrict__ raw, const float* __restrict__ W1,
             const int* __restrict__ vnum, float* __restrict__ part)
{
    __shared__ __align__(16) char smem[57344];
    __shared__ char act[NROWS];
    const int t = threadIdx.x;
    const int c = blockIdx.x;
    const int d0 = c * KC;
    if (t < NROWS) act[t] = ((t % NV) < vnum[t / NV]) ? 1 : 0;
    __syncthreads();

    // ---- A staging: 3 passes, idx=p*512+t: row=idx>>3 (0..191), kq=idx&7 ----
    int akq[3];
    bool aact[3];
    const float* aptr[3];
    int awoff[3];
#pragma unroll
    for (int p = 0; p < 3; ++p) {
        int idx = p * 512 + t;
        int row = idx >> 3, kq = idx & 7;
        akq[p] = kq;
        aact[p] = act[row] != 0;
        aptr[p] = raw + (size_t)row * DRAW + d0 + kq * 4;
        awoff[p] = ABASE + (row >> 5) * 4096 + (kq >> 2) * 2048
                 + (((row & 31) + ((kq >> 1) & 1) * 32) << 4) + ((kq & 1) << 3);
    }
    // ---- B staging: col = t&255, khalf = t>>8 (16 k each) ----
    const int col = t & 255;
    const int khalf = t >> 8;
    const int ks = khalf * 16;
    const float* bptr = W1 + (size_t)(d0 + ks) * KOUT + col;
    int bwoff[2];
#pragma unroll
    for (int og = 0; og < 2; ++og)
        bwoff[og] = BBASE + ((col >> 5) << 12) + (khalf << 11)
                  + (((col & 31) + og * 32) << 4);

    // wave/fragment geometry: 2(M) x 4(N)
    const int lane = t & 63;
    const int wave = t >> 6;
    const int wm = wave >> 2, wn = wave & 3;

    f32x16 acc[3][2];
#pragma unroll
    for (int i = 0; i < 3; ++i)
#pragma unroll
        for (int j = 0; j < 2; ++j)
#pragma unroll
            for (int r = 0; r < 16; ++r) acc[i][j][r] = 0.f;

    float4 A0[3], A1[3];
    float B0r[16], B1r[16];
    K1_LOAD(A0, B0r, 0);

#pragma unroll 1
    for (int sp = 0; sp < 12; ++sp) {
        K1_STEP(A0, B0r, A1, B1r, 2 * sp, 1);
        K1_STEP(A1, B1r, A0, B0r, 2 * sp + 1, 1);
    }
    K1_STEP(A0, B0r, A1, B1r, 24, 0);

    // ---- epilogue: part[row][chunk][col]; 32x32 C/D layout (m74/m101):
    // col = lane&31, row = (r&3) + 8*(r>>2) + 4*(lane>>5), r in [0,16)
    const int l31 = lane & 31, lh = lane >> 5;
#pragma unroll
    for (int tm = 0; tm < 3; ++tm) {
        int rowb = wm * 96 + tm * 32 + 4 * lh;
#pragma unroll
        for (int tn = 0; tn < 2; ++tn) {
            int colx = wn * 64 + tn * 32 + l31;
            f32x16 a = acc[tm][tn];
#pragma unroll
            for (int r = 0; r < 16; ++r) {
                int grow = rowb + (r & 3) + 8 * (r >> 2);
                part[((size_t)grow * NCHUNK + c) * KOUT + colx] = a[r];
            }
        }
    }
}

// fused 256-chunk reduce + score head. One block per row; part[row] is a
// CONTIGUOUS 256KB stream -> coalesced. (verified R7/R10/R11)
__global__ __launch_bounds__(1024)
void k2_score(const float* __restrict__ part, const float* __restrict__ b1,
              const float* __restrict__ W2, const float* __restrict__ b2,
              float* __restrict__ score)
{
    const int row = blockIdx.x, t = threadIdx.x;
    const int col = t & 255, cg = t >> 8;
    __shared__ float red[4][KOUT];
    __shared__ float r2[4];
    const float* p = part + ((size_t)row * NCHUNK + cg * 64) * KOUT + col;
    float s = 0.f;
#pragma unroll 8
    for (int i = 0; i < 64; ++i) s += p[(size_t)i * KOUT];
    red[cg][col] = s;
    __syncthreads();
    if (t < 256) {
        float v = red[0][col] + red[1][col] + red[2][col] + red[3][col];
        float h = fmaxf(v + b1[col], 0.f) * W2[col];
        for (int o = 32; o > 0; o >>= 1) h += __shfl_down(h, o, 64);
        if ((t & 63) == 0) r2[t >> 6] = h;
    }
    __syncthreads();
    if (t == 0) {
        float sm = r2[0] + r2[1] + r2[2] + r2[3];
        float sraw = fmaxf(sm + b2[0], 0.f);
        score[row] = 1.f / (1.f + expf(-tanhf(fabsf(sraw))));
    }
}

// fused tail: binning->coeff->desc->3-layer classifier. One block per sample.
// (verified R4/R9/R11)
__global__ __launch_bounds__(512)
void k5f(const float* __restrict__ score, const int* __restrict__ vnum,
         const float* __restrict__ fv,
         const float* __restrict__ Wf1, const float* __restrict__ bf1,
         const float* __restrict__ Wf2, const float* __restrict__ bf2,
         const float* __restrict__ Wl,  const float* __restrict__ bl,
         float* __restrict__ out)
{
    const int n = blockIdx.x, t = threadIdx.x;
    __shared__ float coeffL[NV], descL[DFEAT], z1L[512], z2L[256];
    __shared__ float wsum[NG], wt[NG], outred[8][NCLS];
    __shared__ int cnt[NG];
    __shared__ float wtotS;
    if (t < NG) { cnt[t] = 0; wsum[t] = 0.f; }
    __syncthreads();
    const int vn = vnum[n];
    const bool act = (t < NV) && (t < vn);
    float sc = 0.f; int b = 0;
    if (act) {
        sc = score[n * NV + t];
        b = (int)floorf(sc * 8.f); b = b < 0 ? 0 : (b > 7 ? 7 : b);
        atomicAdd(&cnt[b], 1);
    }
    __syncthreads();
    if (act) atomicAdd(&wsum[b], ceilf(sc * (float)cnt[b]));
    __syncthreads();
    if (t < NG) wt[t] = (cnt[t] > 0) ? wsum[t] / (float)cnt[t] : 0.f;
    __syncthreads();
    if (t == 0) { float x = 0.f; for (int g = 0; g < NG; ++g) x += wt[g]; wtotS = x; }
    __syncthreads();
    if (t < NV) coeffL[t] = act ? wt[b] / ((float)cnt[b] * wtotS) : 0.f;
    __syncthreads();
#pragma unroll
    for (int p = 0; p < 2; ++p) {
        int d = t + p * 512;
        float a = 0.f;
#pragma unroll
        for (int v = 0; v < NV; ++v)
            a = fmaf(coeffL[v], fv[((size_t)n * NV + v) * DFEAT + d], a);
        descL[d] = a;
    }
    __syncthreads();
    {
        float a = 0.f;
#pragma unroll 8
        for (int d = 0; d < DFEAT; ++d)
            a = fmaf(descL[d], Wf1[(size_t)d * 512 + t], a);
        z1L[t] = fmaxf(a + bf1[t], 0.f);
    }
    __syncthreads();
    if (t < 256) {
        float a = 0.f;
#pragma unroll 8
        for (int d = 0; d < 512; ++d)
            a = fmaf(z1L[d], Wf2[(size_t)d * 256 + t], a);
        z2L[t] = fmaxf(a + bf2[t], 0.f);
    }
    __syncthreads();
    if (t < 320) {
        int j = t % NCLS, seg = t / NCLS;
        float a = 0.f;
#pragma unroll
        for (int dd = 0; dd < 32; ++dd) {
            int d = seg * 32 + dd;
            a = fmaf(z2L[d], Wl[d * NCLS + j], a);
        }
        outred[seg][j] = a;
    }
    __syncthreads();
    if (t < NCLS) {
        float a = bl[t];
#pragma unroll
        for (int s8 = 0; s8 < 8; ++s8) a += outred[s8][t];
        out[n * NCLS + t] = a;
    }
}

extern "C" void kernel_launch(void* const* d_in, const int* in_sizes, int n_in,
                              void* d_out, int out_size, void* d_ws, size_t ws_size,
                              hipStream_t stream)
{
    const float* raw  = (const float*)d_in[0];
    const float* fv   = (const float*)d_in[1];
    const int*   vnum = (const int*)d_in[2];
    const float* W1   = (const float*)d_in[3];
    const float* b1   = (const float*)d_in[4];
    const float* W2   = (const float*)d_in[5];
    const float* b2   = (const float*)d_in[6];
    const float* Wf1  = (const float*)d_in[7];
    const float* bf1  = (const float*)d_in[8];
    const float* Wf2  = (const float*)d_in[9];
    const float* bf2  = (const float*)d_in[10];
    const float* Wl   = (const float*)d_in[11];
    const float* bl   = (const float*)d_in[12];
    float* out = (float*)d_out;
    char* ws = (char*)d_ws;
    float* score = (float*)(ws + WS_SCORE);
    float* part  = (float*)(ws + WS_PART);

    k1_mfma<<<NCHUNK, 512, 0, stream>>>(raw, W1, vnum, part);
    k2_score<<<NROWS, 1024, 0, stream>>>(part, b1, W2, b2, score);
    k5f<<<NB, 512, 0, stream>>>(score, vnum, fv, Wf1, bf1, Wf2, bf2, Wl, bl, out);
}